// Round 5
// baseline (184.566 us; speedup 1.0000x reference)
//
#include <hip/hip_runtime.h>

namespace {

typedef _Float16 v8h __attribute__((ext_vector_type(8)));
typedef float    v4f __attribute__((ext_vector_type(4)));

constexpr int NMEL = 128;
constexpr int ND   = 64;
constexpr int NK   = 128;
constexpr int NTOK = 32 * 4096;          // 131072
constexpr int TPB  = 256;                // tokens per block
constexpr int GRID = NTOK / TPB;         // 512

// ---------------------------------------------------------------------------
// precomp: all token-independent tables into d_ws.
//   E[j][m] = sum_d cb01[j][d]*w_in[d][m] -> f16 hi/lo, stored SWIZZLED in
//   MFMA-fragment order: chunk(s,c,h,kk) of 1 KB; element lane*16B + e*2B
//   holds E[s*128 + c*16 + (lane&15)][kk*32 + (lane>>4)*8 + e].
//   nh[j] = 0.5||c_j||^2 - b_in.c_j ; G[a][b] = cb0_a.cb1_b ;
//   Dec0[a][m] = cb0_a.w_out_m + b_out_m ; Dec1[b][m] = cb1_b.w_out_m.
// ---------------------------------------------------------------------------
__global__ __launch_bounds__(256) void precomp(
    const float* __restrict__ w_in, const float* __restrict__ b_in,
    const float* __restrict__ cb0, const float* __restrict__ cb1,
    const float* __restrict__ w_out, const float* __restrict__ b_out,
    float* __restrict__ dec0, float* __restrict__ dec1,
    float* __restrict__ G, float* __restrict__ nh,
    _Float16* __restrict__ E_swz) {
  const int j = blockIdx.x;          // 0..255
  const int tid = threadIdx.x;
  const float* __restrict__ crow = (j < NK) ? (cb0 + j * ND) : (cb1 + (j - NK) * ND);

  if (tid < NMEL) {
    const int m = tid;
    float e = 0.f;
#pragma unroll
    for (int d = 0; d < ND; ++d) e += crow[d] * w_in[d * NMEL + m];
    const _Float16 hi = (_Float16)e;
    const _Float16 lo = (_Float16)(e - (float)hi);
    const int s = j >> 7, jj = j & 127, c = jj >> 4, mr = jj & 15;
    const int kk = m >> 5, q = (m >> 3) & 3, ei = m & 7;
    const int lane = q * 16 + mr;
    const size_t base = ((((size_t)s * 8 + c) * 8) + kk) * 512;  // h=0 chunk (halves)
    E_swz[base + lane * 8 + ei] = hi;
    E_swz[base + 2048 + lane * 8 + ei] = lo;                     // h=1 chunk
  } else {
    const int m = tid - NMEL;
    const float4* wr = (const float4*)(w_out + m * ND);
    const float4* cr4 = (const float4*)crow;
    float a = 0.f;
#pragma unroll
    for (int qq = 0; qq < ND / 4; ++qq) {
      const float4 w4 = wr[qq], c4 = cr4[qq];
      a += c4.x * w4.x + c4.y * w4.y + c4.z * w4.z + c4.w * w4.w;
    }
    if (j < NK) dec0[j * NMEL + m] = a + b_out[m];
    else        dec1[(j - NK) * NMEL + m] = a;
    if (j < NK) {
      const float4* c1r = (const float4*)(cb1 + m * ND);
      float g = 0.f;
#pragma unroll
      for (int qq = 0; qq < ND / 4; ++qq) {
        const float4 c4 = cr4[qq], d4 = c1r[qq];
        g += c4.x * d4.x + c4.y * d4.y + c4.z * d4.z + c4.w * d4.w;
      }
      G[j * NK + m] = g;
    }
  }
  if (tid < 64) {  // whole first wave: nh[j] via butterfly reduce
    const float v = crow[tid];
    float t = 0.5f * v * v - b_in[tid] * v;
#pragma unroll
    for (int d = 1; d < 64; d <<= 1) t += __shfl_xor(t, d);
    if (tid == 0) nh[j] = t;
  }
}

// ---------------------------------------------------------------------------
// main: block = 512 thr (8 waves), 256 tokens (2 tiles of 16 per wave).
// E staged per stage in 64 KB LDS (fragment order -> conflict-free b128).
// 64 KB LDS + <=128 VGPR -> 2 blocks/CU = 16 waves/CU (~50% occupancy);
// the co-resident block overlaps our barriers.
// ---------------------------------------------------------------------------
__global__ __launch_bounds__(512, 4) void rvq_main(
    const float* __restrict__ mel,
    const _Float16* __restrict__ E_swz,
    const float* __restrict__ nh,
    const float* __restrict__ G,
    const float* __restrict__ dec0,
    const float* __restrict__ dec1,
    float* __restrict__ out) {
  __shared__ _Float16 sE[32768];   // 64 KB = one stage of E (hi+lo)
  const int tid = threadIdx.x;
  const int wv = tid >> 6;         // 0..7
  const int ln = tid & 63;
  const int m  = ln & 15;
  const int q  = ln >> 4;

  // ---- issue stage-0 fill (direct-to-LDS DMA, contiguous) ----
  {
    const char* g = (const char*)E_swz;
    char* l = (char*)sE;
#pragma unroll
    for (int it = 0; it < 8; ++it) {
      __builtin_amdgcn_global_load_lds(
          (const __attribute__((address_space(1))) void*)(g + it * 8192 + wv * 1024 + ln * 16),
          (__attribute__((address_space(3))) void*)(l + it * 8192 + wv * 1024),
          16, 0, 0);
    }
  }
  __syncthreads();   // E0 resident; A-loads issued after so waves pipeline freely

  // ---- A fragments: 2 tiles x 16 tokens, fp32 -> f16 hi+lo ----
  v8h a_hi[2][4], a_lo[2][4];
#pragma unroll
  for (int t = 0; t < 2; ++t) {
    const int tok0 = blockIdx.x * TPB + wv * 32 + t * 16;
    const float* xr = mel + (size_t)(tok0 + m) * NMEL + q * 8;
#pragma unroll
    for (int kk = 0; kk < 4; ++kk) {
      const float4 x0 = *(const float4*)(xr + kk * 32);
      const float4 x1 = *(const float4*)(xr + kk * 32 + 4);
      const float xs[8] = {x0.x, x0.y, x0.z, x0.w, x1.x, x1.y, x1.z, x1.w};
#pragma unroll
      for (int e = 0; e < 8; ++e) {
        const _Float16 h = (_Float16)xs[e];
        a_hi[t][kk][e] = h;
        a_lo[t][kk][e] = (_Float16)(xs[e] - (float)h);
      }
    }
  }

  float nhv[8];
#pragma unroll
  for (int c = 0; c < 8; ++c) nhv[c] = nh[c * 16 + m];

  float bv[2][4];
  int   bi[2][4];
  int   s0i[2][4], s1i[2][4];

  // ================= stage 0 =================
#pragma unroll
  for (int t = 0; t < 2; ++t)
#pragma unroll
    for (int i = 0; i < 4; ++i) { bv[t][i] = 3.4e38f; bi[t][i] = 0; }

#pragma unroll
  for (int c = 0; c < 8; ++c) {
    v8h bh[4], bl[4];
#pragma unroll
    for (int kk = 0; kk < 4; ++kk) {
      bh[kk] = *(const v8h*)(sE + (c * 8 + kk) * 512 + ln * 8);
      bl[kk] = *(const v8h*)(sE + (c * 8 + 4 + kk) * 512 + ln * 8);
    }
    v4f a0 = (v4f){0.f, 0.f, 0.f, 0.f}, a1 = a0;
#pragma unroll
    for (int kk = 0; kk < 4; ++kk) {
      a0 = __builtin_amdgcn_mfma_f32_16x16x32_f16(a_hi[0][kk], bh[kk], a0, 0, 0, 0);
      a1 = __builtin_amdgcn_mfma_f32_16x16x32_f16(a_hi[1][kk], bh[kk], a1, 0, 0, 0);
      a0 = __builtin_amdgcn_mfma_f32_16x16x32_f16(a_lo[0][kk], bh[kk], a0, 0, 0, 0);
      a1 = __builtin_amdgcn_mfma_f32_16x16x32_f16(a_lo[1][kk], bh[kk], a1, 0, 0, 0);
      a0 = __builtin_amdgcn_mfma_f32_16x16x32_f16(a_hi[0][kk], bl[kk], a0, 0, 0, 0);
      a1 = __builtin_amdgcn_mfma_f32_16x16x32_f16(a_hi[1][kk], bl[kk], a1, 0, 0, 0);
    }
    const float nv = nhv[c];
    const int jj = c * 16 + m;
#pragma unroll
    for (int i = 0; i < 4; ++i) {
      const float s0 = nv - a0[i];
      if (s0 < bv[0][i]) { bv[0][i] = s0; bi[0][i] = jj; }
      const float s1 = nv - a1[i];
      if (s1 < bv[1][i]) { bv[1][i] = s1; bi[1][i] = jj; }
    }
  }
#pragma unroll
  for (int d = 1; d < 16; d <<= 1)
#pragma unroll
    for (int t = 0; t < 2; ++t)
#pragma unroll
      for (int i = 0; i < 4; ++i) {
        const float ov = __shfl_xor(bv[t][i], d);
        const int   oi = __shfl_xor(bi[t][i], d);
        if (ov < bv[t][i] || (ov == bv[t][i] && oi < bi[t][i])) { bv[t][i] = ov; bi[t][i] = oi; }
      }
#pragma unroll
  for (int t = 0; t < 2; ++t)
#pragma unroll
    for (int i = 0; i < 4; ++i) s0i[t][i] = bi[t][i];

  __syncthreads();   // all waves done reading stage-0 LDS

  // ---- issue stage-1 fill; overlap with nh/G preloads ----
  {
    const char* g = (const char*)(E_swz + 32768);
    char* l = (char*)sE;
#pragma unroll
    for (int it = 0; it < 8; ++it) {
      __builtin_amdgcn_global_load_lds(
          (const __attribute__((address_space(1))) void*)(g + it * 8192 + wv * 1024 + ln * 16),
          (__attribute__((address_space(3))) void*)(l + it * 8192 + wv * 1024),
          16, 0, 0);
    }
  }
#pragma unroll
  for (int c = 0; c < 8; ++c) nhv[c] = nh[NK + c * 16 + m];
  float gc[2][4];
#pragma unroll
  for (int t = 0; t < 2; ++t)
#pragma unroll
    for (int i = 0; i < 4; ++i) gc[t][i] = G[(size_t)s0i[t][i] * NK + m];  // c=0

  __syncthreads();   // stage-1 fill complete

  // ================= stage 1 =================
#pragma unroll
  for (int t = 0; t < 2; ++t)
#pragma unroll
    for (int i = 0; i < 4; ++i) { bv[t][i] = 3.4e38f; bi[t][i] = 0; }

#pragma unroll
  for (int c = 0; c < 8; ++c) {
    v8h bh[4], bl[4];
#pragma unroll
    for (int kk = 0; kk < 4; ++kk) {
      bh[kk] = *(const v8h*)(sE + (c * 8 + kk) * 512 + ln * 8);
      bl[kk] = *(const v8h*)(sE + (c * 8 + 4 + kk) * 512 + ln * 8);
    }
    float gn[2][4];
    if (c < 7) {
#pragma unroll
      for (int t = 0; t < 2; ++t)
#pragma unroll
        for (int i = 0; i < 4; ++i)
          gn[t][i] = G[(size_t)s0i[t][i] * NK + (c + 1) * 16 + m];
    }
    v4f a0 = (v4f){0.f, 0.f, 0.f, 0.f}, a1 = a0;
#pragma unroll
    for (int kk = 0; kk < 4; ++kk) {
      a0 = __builtin_amdgcn_mfma_f32_16x16x32_f16(a_hi[0][kk], bh[kk], a0, 0, 0, 0);
      a1 = __builtin_amdgcn_mfma_f32_16x16x32_f16(a_hi[1][kk], bh[kk], a1, 0, 0, 0);
      a0 = __builtin_amdgcn_mfma_f32_16x16x32_f16(a_lo[0][kk], bh[kk], a0, 0, 0, 0);
      a1 = __builtin_amdgcn_mfma_f32_16x16x32_f16(a_lo[1][kk], bh[kk], a1, 0, 0, 0);
      a0 = __builtin_amdgcn_mfma_f32_16x16x32_f16(a_hi[0][kk], bl[kk], a0, 0, 0, 0);
      a1 = __builtin_amdgcn_mfma_f32_16x16x32_f16(a_hi[1][kk], bl[kk], a1, 0, 0, 0);
    }
    const float nv = nhv[c];
    const int jj = c * 16 + m;
#pragma unroll
    for (int i = 0; i < 4; ++i) {
      const float s0 = nv + gc[0][i] - a0[i];
      if (s0 < bv[0][i]) { bv[0][i] = s0; bi[0][i] = jj; }
      const float s1 = nv + gc[1][i] - a1[i];
      if (s1 < bv[1][i]) { bv[1][i] = s1; bi[1][i] = jj; }
    }
    if (c < 7) {
#pragma unroll
      for (int t = 0; t < 2; ++t)
#pragma unroll
        for (int i = 0; i < 4; ++i) gc[t][i] = gn[t][i];
    }
  }
#pragma unroll
  for (int d = 1; d < 16; d <<= 1)
#pragma unroll
    for (int t = 0; t < 2; ++t)
#pragma unroll
      for (int i = 0; i < 4; ++i) {
        const float ov = __shfl_xor(bv[t][i], d);
        const int   oi = __shfl_xor(bi[t][i], d);
        if (ov < bv[t][i] || (ov == bv[t][i] && oi < bi[t][i])) { bv[t][i] = ov; bi[t][i] = oi; }
      }
#pragma unroll
  for (int t = 0; t < 2; ++t)
#pragma unroll
    for (int i = 0; i < 4; ++i) s1i[t][i] = bi[t][i];

  // ---- epilogue: out = Dec0[s0] + Dec1[s1] ----
#pragma unroll
  for (int t = 0; t < 2; ++t)
#pragma unroll
    for (int i = 0; i < 4; ++i) {
      const int tok = blockIdx.x * TPB + wv * 32 + t * 16 + q * 4 + i;
      const float4* p0 = (const float4*)(dec0 + (size_t)s0i[t][i] * NMEL + m * 8);
      const float4* p1 = (const float4*)(dec1 + (size_t)s1i[t][i] * NMEL + m * 8);
      float4* o = (float4*)(out + (size_t)tok * NMEL + m * 8);
      const float4 u0 = p0[0], u1 = p0[1], w0 = p1[0], w1 = p1[1];
      float4 r0, r1;
      r0.x = u0.x + w0.x; r0.y = u0.y + w0.y; r0.z = u0.z + w0.z; r0.w = u0.w + w0.w;
      r1.x = u1.x + w1.x; r1.y = u1.y + w1.y; r1.z = u1.z + w1.z; r1.w = u1.w + w1.w;
      o[0] = r0; o[1] = r1;
    }
}

}  // namespace

extern "C" void kernel_launch(void* const* d_in, const int* in_sizes, int n_in,
                              void* d_out, int out_size, void* d_ws, size_t ws_size,
                              hipStream_t stream) {
  const float* mel   = (const float*)d_in[0];
  const float* w_in  = (const float*)d_in[1];
  const float* b_in  = (const float*)d_in[2];
  const float* cb0   = (const float*)d_in[3];
  const float* cb1   = (const float*)d_in[4];
  const float* w_out = (const float*)d_in[5];
  const float* b_out = (const float*)d_in[6];
  float* out = (float*)d_out;

  // ws: dec0 | dec1 | G | nh | E_swz  (64+64+64+1+128 KB ~ 321 KB)
  float* dec0 = (float*)d_ws;
  float* dec1 = dec0 + NK * NMEL;
  float* G    = dec1 + NK * NMEL;
  float* nh   = G + NK * NK;
  _Float16* E_swz = (_Float16*)(nh + 2 * NK);

  hipLaunchKernelGGL(precomp, dim3(2 * NK), dim3(256), 0, stream,
                     w_in, b_in, cb0, cb1, w_out, b_out, dec0, dec1, G, nh, E_swz);
  hipLaunchKernelGGL(rvq_main, dim3(GRID), dim3(512), 0, stream,
                     mel, E_swz, nh, G, dec0, dec1, out);
}